// Round 3
// baseline (26995.514 us; speedup 1.0000x reference)
//
#include <hip/hip_runtime.h>
#include <hip/hip_bf16.h>
#include <math.h>

// Problem constants
#define VV 50257
#define II 1024
#define HH 1024
#define OO 50257
#define TT 4096
#define GWG 64    // scan workgroups (512 thr each; 64 WGs on 256 CUs -> co-resident)

// ---------------------------------------------------------------------------
// GEMM (NT): C[M,N] = A[M,K] * B[N,K]^T + bias[N]
// If tokens != nullptr, A-row m is embed[tokens[m]] (fused embedding gather).
// 64x64 tile, BK=32, 256 threads, 4x4 accumulators per thread. fp32.
// ---------------------------------------------------------------------------
__global__ __launch_bounds__(256, 2) void gemm_nt(
    const float* __restrict__ A, const float* __restrict__ Bw,
    const float* __restrict__ bias, float* __restrict__ C,
    int M, int N, int K,
    const int* __restrict__ tokens, const float* __restrict__ embed)
{
    __shared__ float As[32][68];   // [k][row], padded (16B rows, conflict-light)
    __shared__ float Bs[32][68];

    const int tid = threadIdx.x;
    const int bm = blockIdx.y * 64;
    const int bn = blockIdx.x * 64;
    const int tx = tid & 15;       // output col group
    const int ty = tid >> 4;       // output row group
    const int lr = tid >> 2;       // staging row in tile (0..63)
    const int lk = (tid & 3) * 8;  // staging k offset (0,8,16,24)

    const float* Arow;
    if (tokens) Arow = embed + (size_t)tokens[bm + lr] * K + lk;
    else        Arow = A + (size_t)(bm + lr) * K + lk;
    const float* Brow = Bw + (size_t)(bn + lr) * K + lk;

    float acc[4][4] = {};

    for (int k0 = 0; k0 < K; k0 += 32) {
        float4 a0 = *(const float4*)(Arow + k0);
        float4 a1 = *(const float4*)(Arow + k0 + 4);
        float4 b0 = *(const float4*)(Brow + k0);
        float4 b1 = *(const float4*)(Brow + k0 + 4);
        __syncthreads();   // protect previous iteration's LDS reads
        As[lk + 0][lr] = a0.x; As[lk + 1][lr] = a0.y; As[lk + 2][lr] = a0.z; As[lk + 3][lr] = a0.w;
        As[lk + 4][lr] = a1.x; As[lk + 5][lr] = a1.y; As[lk + 6][lr] = a1.z; As[lk + 7][lr] = a1.w;
        Bs[lk + 0][lr] = b0.x; Bs[lk + 1][lr] = b0.y; Bs[lk + 2][lr] = b0.z; Bs[lk + 3][lr] = b0.w;
        Bs[lk + 4][lr] = b1.x; Bs[lk + 5][lr] = b1.y; Bs[lk + 6][lr] = b1.z; Bs[lk + 7][lr] = b1.w;
        __syncthreads();
        #pragma unroll
        for (int k = 0; k < 32; ++k) {
            float4 av = *(const float4*)&As[k][ty * 4];
            float4 bv = *(const float4*)&Bs[k][tx * 4];
            float a4[4] = {av.x, av.y, av.z, av.w};
            float b4[4] = {bv.x, bv.y, bv.z, bv.w};
            #pragma unroll
            for (int i = 0; i < 4; ++i)
                #pragma unroll
                for (int j = 0; j < 4; ++j)
                    acc[i][j] = fmaf(a4[i], b4[j], acc[i][j]);
        }
    }

    float4 bb = *(const float4*)(bias + bn + tx * 4);
    const float b4[4] = {bb.x, bb.y, bb.z, bb.w};
    #pragma unroll
    for (int i = 0; i < 4; ++i) {
        float4 o;
        o.x = acc[i][0] + b4[0];
        o.y = acc[i][1] + b4[1];
        o.z = acc[i][2] + b4[2];
        o.w = acc[i][3] + b4[3];
        *(float4*)(C + (size_t)(bm + ty * 4 + i) * N + bn + tx * 4) = o;
    }
}

// ---------------------------------------------------------------------------
// Persistent GRU scan. 64 WGs x 512 threads; wave w of WG g owns hidden units
// j0 = g*16 + 2*w and j1 = j0+1. Lane split: rl = lane>>4 selects the gate
// row (j + rl*1024; rl==3 duplicates rl==0, results unused), c = lane&15
// selects a 64-float k-chunk. Both units' weight slices live in VGPRs
// (128 floats/lane, ~190 VGPR total).
// NOTE: __launch_bounds__(512) — NOT (512,2): min-2-waves/EU would cap the
// allocator at 128 VGPR and force a full spill of the weight arrays. With
// 512 threads the backend already budgets <=256 VGPR (2 waves/SIMD fit).
// Per step: shared h-chunk loads feed 4 independent FMA chains, 16-lane
// shfl_xor reduce, gates on lanes 0..1 (one unit each), agent-scope atomic
// h store, then a grid-wide monotonic-counter sync (release add, acquire
// fence, s_sleep backoff).
// ---------------------------------------------------------------------------
__global__ __launch_bounds__(512) void scan_gru(
    const float* __restrict__ w_hh, const float* __restrict__ b_hh,
    const float* __restrict__ gi, float* __restrict__ hbuf,
    unsigned* __restrict__ cnt)
{
    const int tid  = threadIdx.x;
    const int wave = tid >> 6;
    const int lane = tid & 63;
    const int rl0  = lane >> 4;
    const int c    = lane & 15;
    const int rl   = (rl0 < 3) ? rl0 : 0;        // rl==3 lanes duplicate rl==0
    const int j0   = blockIdx.x * 16 + wave * 2; // even, 0..1022
    const int row0 = j0 + rl * 1024;             // unit0 row; unit1 = row0+1

    // One-time preload of both units' weight slices into VGPRs.
    float w0[64], w1[64];
    {
        const float4* wr0 = (const float4*)(w_hh + (size_t)row0 * 1024 + c * 64);
        const float4* wr1 = (const float4*)(w_hh + (size_t)(row0 + 1) * 1024 + c * 64);
        #pragma unroll
        for (int m = 0; m < 16; ++m) {
            float4 a = wr0[m], b = wr1[m];
            w0[4*m+0] = a.x; w0[4*m+1] = a.y; w0[4*m+2] = a.z; w0[4*m+3] = a.w;
            w1[4*m+0] = b.x; w1[4*m+1] = b.y; w1[4*m+2] = b.z; w1[4*m+3] = b.w;
        }
    }
    const float2 bh = *(const float2*)(b_hh + row0);
    const float* gp = gi + row0;                 // gi[t][row0], stride 3072/step

    float2 gl = *(const float2*)gp;              // prefetched gi[t][row0..row0+1]
    for (int t = 0; t < TT; ++t) {
        const float* cur = hbuf + ((t & 1) ? HH : 0);
        float* nxt       = hbuf + ((t & 1) ? 0 : HH);

        // Early independent loads: next step's gi and the z-gate's h_old.
        float2 gln = make_float2(0.f, 0.f);
        if (t + 1 < TT) gln = *(const float2*)(gp + (size_t)(t + 1) * 3072);
        const float hold = cur[j0 + (lane & 1)]; // lanes 0/1 use it; others harmless

        // Partial dots for both units over this lane's 64-float h chunk.
        const float4* hp = (const float4*)(cur + c * 64);
        float a00 = 0.f, a01 = 0.f, a10 = 0.f, a11 = 0.f;
        #pragma unroll
        for (int m = 0; m < 16; m += 2) {
            float4 x = hp[m], y = hp[m + 1];
            a00 = fmaf(w0[4*m+0], x.x, a00); a10 = fmaf(w1[4*m+0], x.x, a10);
            a00 = fmaf(w0[4*m+1], x.y, a00); a10 = fmaf(w1[4*m+1], x.y, a10);
            a00 = fmaf(w0[4*m+2], x.z, a00); a10 = fmaf(w1[4*m+2], x.z, a10);
            a00 = fmaf(w0[4*m+3], x.w, a00); a10 = fmaf(w1[4*m+3], x.w, a10);
            a01 = fmaf(w0[4*m+4], y.x, a01); a11 = fmaf(w1[4*m+4], y.x, a11);
            a01 = fmaf(w0[4*m+5], y.y, a01); a11 = fmaf(w1[4*m+5], y.y, a11);
            a01 = fmaf(w0[4*m+6], y.z, a01); a11 = fmaf(w1[4*m+6], y.z, a11);
            a01 = fmaf(w0[4*m+7], y.w, a01); a11 = fmaf(w1[4*m+7], y.w, a11);
        }
        float acc0 = a00 + a01, acc1 = a10 + a11;

        // Reduce across the 16 chunk lanes (stays inside each rl group).
        acc0 += __shfl_xor(acc0, 1);  acc1 += __shfl_xor(acc1, 1);
        acc0 += __shfl_xor(acc0, 2);  acc1 += __shfl_xor(acc1, 2);
        acc0 += __shfl_xor(acc0, 4);  acc1 += __shfl_xor(acc1, 4);
        acc0 += __shfl_xor(acc0, 8);  acc1 += __shfl_xor(acc1, 8);

        const float s0 = acc0 + bh.x, s1 = acc1 + bh.y;   // gh[row]
        const float v0 = s0 + gl.x,   v1 = s1 + gl.y;     // gi+gh preact
        const float vz0 = __shfl(v0, 16), vz1 = __shfl(v1, 16);  // z preact
        const float sn0 = __shfl(s0, 32), sn1 = __shfl(s1, 32);  // h_n (gh only)
        const float gn0 = __shfl(gl.x, 32), gn1 = __shfl(gl.y, 32); // i_n

        if (lane < 2) {
            const float vr = lane ? v1  : v0;
            const float vz = lane ? vz1 : vz0;
            const float sn = lane ? sn1 : sn0;
            const float gn = lane ? gn1 : gn0;
            const float r = 1.f / (1.f + expf(-vr));
            const float z = 1.f / (1.f + expf(-vz));
            const float n = tanhf(gn + r * sn);
            const float hnew = (1.f - z) * n + z * hold;
            // agent-scope atomic store -> lands at the device coherence point
            __hip_atomic_store(&nxt[j0 + lane], hnew,
                               __ATOMIC_RELAXED, __HIP_MEMORY_SCOPE_AGENT);
        }
        gl = gln;

        // Grid sync: monotonic counter, target (t+1)*GWG.
        // __syncthreads drains each wave's vmcnt (h stores complete); the
        // RELEASE add architecturally publishes them before the increment.
        __syncthreads();
        if (tid == 0) {
            __hip_atomic_fetch_add(cnt, 1u, __ATOMIC_RELEASE,
                                   __HIP_MEMORY_SCOPE_AGENT);
            const unsigned tgt = (unsigned)(t + 1) * GWG;
            while (__hip_atomic_load(cnt, __ATOMIC_RELAXED,
                                     __HIP_MEMORY_SCOPE_AGENT) < tgt)
                __builtin_amdgcn_s_sleep(1);
            __builtin_amdgcn_fence(__ATOMIC_ACQUIRE, "agent"); // inv L1/L2
        }
        __syncthreads();
    }
}

// ---------------------------------------------------------------------------
// logits[o] = dot(h, h2o_w[o]) + h2o_b[o]; one wave per output row.
// ---------------------------------------------------------------------------
__global__ __launch_bounds__(256, 4) void logits_k(
    const float* __restrict__ h, const float* __restrict__ Wm,
    const float* __restrict__ b, float* __restrict__ out, int O, int K)
{
    const int lane = threadIdx.x & 63;
    const int o = blockIdx.x * 4 + (threadIdx.x >> 6);
    if (o >= O) return;
    const float* wr = Wm + (size_t)o * K;
    float acc = 0.f;
    #pragma unroll
    for (int m = 0; m < 4; ++m) {
        float4 wv = *(const float4*)(wr + lane * 4 + m * 256);
        float4 hv = *(const float4*)(h + lane * 4 + m * 256);
        acc += wv.x * hv.x + wv.y * hv.y + wv.z * hv.z + wv.w * hv.w;
    }
    #pragma unroll
    for (int d = 32; d; d >>= 1) acc += __shfl_xor(acc, d);
    if (lane == 0) out[o] = acc + b[o];
}

// ---------------------------------------------------------------------------
// log_softmax over 50257 logits, single WG (logits are L2/MALL-resident).
// ---------------------------------------------------------------------------
__global__ __launch_bounds__(1024) void lsm_k(
    const float* __restrict__ logits, float* __restrict__ out, int n)
{
    __shared__ float red[16];
    __shared__ float bc[2];
    const int tid = threadIdx.x;
    const int lane = tid & 63, wv = tid >> 6;

    float m = -3.402823466e38f;
    for (int i = tid; i < n; i += 1024) m = fmaxf(m, logits[i]);
    #pragma unroll
    for (int d = 32; d; d >>= 1) m = fmaxf(m, __shfl_xor(m, d));
    if (lane == 0) red[wv] = m;
    __syncthreads();
    if (tid == 0) {
        float mm = red[0];
        for (int i = 1; i < 16; ++i) mm = fmaxf(mm, red[i]);
        bc[0] = mm;
    }
    __syncthreads();
    const float M = bc[0];

    float s = 0.f;
    for (int i = tid; i < n; i += 1024) s += expf(logits[i] - M);
    #pragma unroll
    for (int d = 32; d; d >>= 1) s += __shfl_xor(s, d);
    if (lane == 0) red[wv] = s;
    __syncthreads();
    if (tid == 0) {
        float ss = 0.f;
        for (int i = 0; i < 16; ++i) ss += red[i];
        bc[1] = logf(ss);
    }
    __syncthreads();
    const float L = bc[1];
    for (int i = tid; i < n; i += 1024) out[i] = logits[i] - M - L;
}

// ---------------------------------------------------------------------------
// Workspace layout (bytes):
//   [0,        8192)   h double buffer (2 x 1024 f32)  -- zeroed each launch
//   [8192,     8448)   sync counter (+pad)             -- zeroed each launch
//   [8448,   209920)   logits (50257 f32, padded)
//   [209920, 16987136) xin   (4096 x 1024 f32)
//   [16987136, 67318784) gi  (4096 x 3072 f32)
// ---------------------------------------------------------------------------
extern "C" void kernel_launch(void* const* d_in, const int* in_sizes, int n_in,
                              void* d_out, int out_size, void* d_ws, size_t ws_size,
                              hipStream_t stream)
{
    const int*   tokens = (const int*)  d_in[0];
    const float* embed  = (const float*)d_in[1];
    const float* i2h_w  = (const float*)d_in[2];
    const float* i2h_b  = (const float*)d_in[3];
    const float* w_ih   = (const float*)d_in[4];
    const float* w_hh   = (const float*)d_in[5];
    const float* b_ih   = (const float*)d_in[6];
    const float* b_hh   = (const float*)d_in[7];
    const float* h2o_w  = (const float*)d_in[8];
    const float* h2o_b  = (const float*)d_in[9];
    float* out = (float*)d_out;

    char* Wb = (char*)d_ws;
    float*    hbuf   = (float*)(Wb);
    unsigned* cnt    = (unsigned*)(Wb + 8192);
    float*    logits = (float*)(Wb + 8448);
    float*    xin    = (float*)(Wb + 209920);
    float*    gi     = (float*)(Wb + 16987136);

    // zero h0 + counter (ws is poisoned 0xAA before every timed launch)
    hipMemsetAsync(Wb, 0, 8448, stream);

    // xin = embed[tokens] @ i2h_w^T + i2h_b        [4096,1024]
    gemm_nt<<<dim3(16, 64), 256, 0, stream>>>(nullptr, i2h_w, i2h_b, xin,
                                              TT, HH, II, tokens, embed);
    // gi = xin @ w_ih^T + b_ih                     [4096,3072]
    gemm_nt<<<dim3(48, 64), 256, 0, stream>>>(xin, w_ih, b_ih, gi,
                                              TT, 3 * HH, HH, nullptr, nullptr);
    // sequential GRU scan (final h lands in hbuf[0..1023], TT even)
    scan_gru<<<GWG, 512, 0, stream>>>(w_hh, b_hh, gi, hbuf, cnt);

    // logits + log_softmax
    logits_k<<<dim3((OO + 3) / 4), 256, 0, stream>>>(hbuf, h2o_w, h2o_b, logits, OO, HH);
    lsm_k<<<1, 1024, 0, stream>>>(logits, out, OO);
}

// Round 4
// 15768.689 us; speedup vs baseline: 1.7120x; 1.7120x over previous
//
#include <hip/hip_runtime.h>
#include <hip/hip_bf16.h>
#include <math.h>

// Problem constants
#define VV 50257
#define II 1024
#define HH 1024
#define OO 50257
#define TT 4096
#define GWG 64    // scan workgroups (512 thr each; 64 WGs on 256 CUs -> co-resident)

// ---------------------------------------------------------------------------
// GEMM (NT): C[M,N] = A[M,K] * B[N,K]^T + bias[N]
// If tokens != nullptr, A-row m is embed[tokens[m]] (fused embedding gather).
// 64x64 tile, BK=32, 256 threads, 4x4 accumulators per thread. fp32.
// ---------------------------------------------------------------------------
__global__ __launch_bounds__(256, 2) void gemm_nt(
    const float* __restrict__ A, const float* __restrict__ Bw,
    const float* __restrict__ bias, float* __restrict__ C,
    int M, int N, int K,
    const int* __restrict__ tokens, const float* __restrict__ embed)
{
    __shared__ float As[32][68];   // [k][row], padded (16B rows, conflict-light)
    __shared__ float Bs[32][68];

    const int tid = threadIdx.x;
    const int bm = blockIdx.y * 64;
    const int bn = blockIdx.x * 64;
    const int tx = tid & 15;       // output col group
    const int ty = tid >> 4;       // output row group
    const int lr = tid >> 2;       // staging row in tile (0..63)
    const int lk = (tid & 3) * 8;  // staging k offset (0,8,16,24)

    const float* Arow;
    if (tokens) Arow = embed + (size_t)tokens[bm + lr] * K + lk;
    else        Arow = A + (size_t)(bm + lr) * K + lk;
    const float* Brow = Bw + (size_t)(bn + lr) * K + lk;

    float acc[4][4] = {};

    for (int k0 = 0; k0 < K; k0 += 32) {
        float4 a0 = *(const float4*)(Arow + k0);
        float4 a1 = *(const float4*)(Arow + k0 + 4);
        float4 b0 = *(const float4*)(Brow + k0);
        float4 b1 = *(const float4*)(Brow + k0 + 4);
        __syncthreads();   // protect previous iteration's LDS reads
        As[lk + 0][lr] = a0.x; As[lk + 1][lr] = a0.y; As[lk + 2][lr] = a0.z; As[lk + 3][lr] = a0.w;
        As[lk + 4][lr] = a1.x; As[lk + 5][lr] = a1.y; As[lk + 6][lr] = a1.z; As[lk + 7][lr] = a1.w;
        Bs[lk + 0][lr] = b0.x; Bs[lk + 1][lr] = b0.y; Bs[lk + 2][lr] = b0.z; Bs[lk + 3][lr] = b0.w;
        Bs[lk + 4][lr] = b1.x; Bs[lk + 5][lr] = b1.y; Bs[lk + 6][lr] = b1.z; Bs[lk + 7][lr] = b1.w;
        __syncthreads();
        #pragma unroll
        for (int k = 0; k < 32; ++k) {
            float4 av = *(const float4*)&As[k][ty * 4];
            float4 bv = *(const float4*)&Bs[k][tx * 4];
            float a4[4] = {av.x, av.y, av.z, av.w};
            float b4[4] = {bv.x, bv.y, bv.z, bv.w};
            #pragma unroll
            for (int i = 0; i < 4; ++i)
                #pragma unroll
                for (int j = 0; j < 4; ++j)
                    acc[i][j] = fmaf(a4[i], b4[j], acc[i][j]);
        }
    }

    float4 bb = *(const float4*)(bias + bn + tx * 4);
    const float b4[4] = {bb.x, bb.y, bb.z, bb.w};
    #pragma unroll
    for (int i = 0; i < 4; ++i) {
        float4 o;
        o.x = acc[i][0] + b4[0];
        o.y = acc[i][1] + b4[1];
        o.z = acc[i][2] + b4[2];
        o.w = acc[i][3] + b4[3];
        *(float4*)(C + (size_t)(bm + ty * 4 + i) * N + bn + tx * 4) = o;
    }
}

// ---------------------------------------------------------------------------
// Persistent GRU scan. 64 WGs x 512 threads; wave w of WG g owns hidden units
// j0 = g*16 + 2*w and j1 = j0+1. Lane split: rl = lane>>4 selects the gate
// row (j + rl*1024; rl==3 duplicates rl==0, results unused), c = lane&15
// selects an INTERLEAVED h-chunk: lane c owns h[m*64 + 4c .. 4c+3], m=0..15
// (so LDS float4 reads are 2-way-conflict-free = free). Both units' weight
// slices live in VGPRs in the matching order (128 floats/lane).
//
// __launch_bounds__(512, 2): min 2 waves/SIMD -> VGPR budget 512/2 = 256,
// enough for the 128 weight floats + working set WITHOUT spill. (Round-3
// profile showed VGPR_Count=84 => full weight spill to scratch; that was
// the 6.4us/step. Verify VGPR_Count ~200 this round.)
//
// Per step: cooperative 4KB h load global->LDS (one per WG, not 16KB/wave
// from MALL), compute from LDS, gates on lanes 0..1, agent-scope h store,
// grid-wide monotonic-counter sync (release add, spin, acquire fence).
// ---------------------------------------------------------------------------
__global__ __launch_bounds__(512, 2) void scan_gru(
    const float* __restrict__ w_hh, const float* __restrict__ b_hh,
    const float* __restrict__ gi, float* __restrict__ hbuf,
    unsigned* __restrict__ cnt)
{
    __shared__ float hs[HH];   // staged h for this step (4 KB)

    const int tid  = threadIdx.x;
    const int wave = tid >> 6;
    const int lane = tid & 63;
    const int rl0  = lane >> 4;
    const int c    = lane & 15;
    const int rl   = (rl0 < 3) ? rl0 : 0;        // rl==3 lanes duplicate rl==0
    const int j0   = blockIdx.x * 16 + wave * 2; // even, 0..1022
    const int row0 = j0 + rl * 1024;             // unit0 row; unit1 = row0+1

    // One-time preload of both units' weight slices into VGPRs, in the
    // interleaved order matching the LDS read pattern:
    //   w0[4m+k] = w_hh[row0][m*64 + 4c + k]
    float w0[64], w1[64];
    {
        const float* wb0 = w_hh + (size_t)row0 * 1024;
        const float* wb1 = wb0 + 1024;
        #pragma unroll
        for (int m = 0; m < 16; ++m) {
            float4 a = *(const float4*)(wb0 + m * 64 + c * 4);
            float4 b = *(const float4*)(wb1 + m * 64 + c * 4);
            w0[4*m+0] = a.x; w0[4*m+1] = a.y; w0[4*m+2] = a.z; w0[4*m+3] = a.w;
            w1[4*m+0] = b.x; w1[4*m+1] = b.y; w1[4*m+2] = b.z; w1[4*m+3] = b.w;
        }
    }
    const float2 bh = *(const float2*)(b_hh + row0);
    const float* gp = gi + row0;                 // gi[t][row0], stride 3072/step

    float2 gl = *(const float2*)gp;              // prefetched gi[t][row0..row0+1]
    for (int t = 0; t < TT; ++t) {
        const float* cur = hbuf + ((t & 1) ? HH : 0);
        float* nxt       = hbuf + ((t & 1) ? 0 : HH);

        // Issue next step's gi prefetch (completes during barrier A's drain;
        // its latency overlaps the h load below).
        float2 gln = make_float2(0.f, 0.f);
        if (t + 1 < TT) gln = *(const float2*)(gp + (size_t)(t + 1) * 3072);

        // Cooperative h stage: 512 threads x float2 = 4 KB global -> LDS.
        *(float2*)(hs + tid * 2) = *(const float2*)(cur + tid * 2);
        __syncthreads();   // barrier A: LDS visible (also drains gln load)

        const float hold = hs[j0 + (lane & 1)];  // lanes 0/1 consume

        // Partial dots for both units over this lane's 16 interleaved float4s.
        const float4* hp = (const float4*)hs;    // hp[m*16 + c] = h[m*64+4c ..]
        float a00 = 0.f, a01 = 0.f, a10 = 0.f, a11 = 0.f;
        #pragma unroll
        for (int m = 0; m < 16; m += 2) {
            float4 x = hp[m * 16 + c];
            float4 y = hp[(m + 1) * 16 + c];
            a00 = fmaf(w0[4*m+0], x.x, a00); a10 = fmaf(w1[4*m+0], x.x, a10);
            a00 = fmaf(w0[4*m+1], x.y, a00); a10 = fmaf(w1[4*m+1], x.y, a10);
            a00 = fmaf(w0[4*m+2], x.z, a00); a10 = fmaf(w1[4*m+2], x.z, a10);
            a00 = fmaf(w0[4*m+3], x.w, a00); a10 = fmaf(w1[4*m+3], x.w, a10);
            a01 = fmaf(w0[4*m+4], y.x, a01); a11 = fmaf(w1[4*m+4], y.x, a11);
            a01 = fmaf(w0[4*m+5], y.y, a01); a11 = fmaf(w1[4*m+5], y.y, a11);
            a01 = fmaf(w0[4*m+6], y.z, a01); a11 = fmaf(w1[4*m+6], y.z, a11);
            a01 = fmaf(w0[4*m+7], y.w, a01); a11 = fmaf(w1[4*m+7], y.w, a11);
        }
        float acc0 = a00 + a01, acc1 = a10 + a11;

        // Reduce across the 16 chunk lanes (stays inside each rl group).
        acc0 += __shfl_xor(acc0, 1);  acc1 += __shfl_xor(acc1, 1);
        acc0 += __shfl_xor(acc0, 2);  acc1 += __shfl_xor(acc1, 2);
        acc0 += __shfl_xor(acc0, 4);  acc1 += __shfl_xor(acc1, 4);
        acc0 += __shfl_xor(acc0, 8);  acc1 += __shfl_xor(acc1, 8);

        const float s0 = acc0 + bh.x, s1 = acc1 + bh.y;   // gh[row]
        const float v0 = s0 + gl.x,   v1 = s1 + gl.y;     // gi+gh preact
        const float vz0 = __shfl(v0, 16), vz1 = __shfl(v1, 16);  // z preact
        const float sn0 = __shfl(s0, 32), sn1 = __shfl(s1, 32);  // h_n (gh only)
        const float gn0 = __shfl(gl.x, 32), gn1 = __shfl(gl.y, 32); // i_n

        if (lane < 2) {
            const float vr = lane ? v1  : v0;
            const float vz = lane ? vz1 : vz0;
            const float sn = lane ? sn1 : sn0;
            const float gn = lane ? gn1 : gn0;
            const float r = 1.f / (1.f + expf(-vr));
            const float z = 1.f / (1.f + expf(-vz));
            const float n = tanhf(gn + r * sn);
            const float hnew = (1.f - z) * n + z * hold;
            // agent-scope atomic store -> lands at the device coherence point
            __hip_atomic_store(&nxt[j0 + lane], hnew,
                               __ATOMIC_RELAXED, __HIP_MEMORY_SCOPE_AGENT);
        }
        gl = gln;

        // Grid sync: monotonic counter, target (t+1)*GWG.
        // Barrier B drains each wave's vmcnt (h stores at coherence point);
        // the RELEASE add then publishes the step before the count moves.
        __syncthreads();
        if (tid == 0) {
            __hip_atomic_fetch_add(cnt, 1u, __ATOMIC_RELEASE,
                                   __HIP_MEMORY_SCOPE_AGENT);
            const unsigned tgt = (unsigned)(t + 1) * GWG;
            while (__hip_atomic_load(cnt, __ATOMIC_RELAXED,
                                     __HIP_MEMORY_SCOPE_AGENT) < tgt)
                __builtin_amdgcn_s_sleep(1);
            __builtin_amdgcn_fence(__ATOMIC_ACQUIRE, "agent"); // inv L1/L2
        }
        __syncthreads();   // barrier C: whole WG sees the fresh step
    }
}

// ---------------------------------------------------------------------------
// logits[o] = dot(h, h2o_w[o]) + h2o_b[o]; one wave per output row.
// ---------------------------------------------------------------------------
__global__ __launch_bounds__(256, 4) void logits_k(
    const float* __restrict__ h, const float* __restrict__ Wm,
    const float* __restrict__ b, float* __restrict__ out, int O, int K)
{
    const int lane = threadIdx.x & 63;
    const int o = blockIdx.x * 4 + (threadIdx.x >> 6);
    if (o >= O) return;
    const float* wr = Wm + (size_t)o * K;
    float acc = 0.f;
    #pragma unroll
    for (int m = 0; m < 4; ++m) {
        float4 wv = *(const float4*)(wr + lane * 4 + m * 256);
        float4 hv = *(const float4*)(h + lane * 4 + m * 256);
        acc += wv.x * hv.x + wv.y * hv.y + wv.z * hv.z + wv.w * hv.w;
    }
    #pragma unroll
    for (int d = 32; d; d >>= 1) acc += __shfl_xor(acc, d);
    if (lane == 0) out[o] = acc + b[o];
}

// ---------------------------------------------------------------------------
// log_softmax over 50257 logits, single WG (logits are L2/MALL-resident).
// ---------------------------------------------------------------------------
__global__ __launch_bounds__(1024) void lsm_k(
    const float* __restrict__ logits, float* __restrict__ out, int n)
{
    __shared__ float red[16];
    __shared__ float bc[2];
    const int tid = threadIdx.x;
    const int lane = tid & 63, wv = tid >> 6;

    float m = -3.402823466e38f;
    for (int i = tid; i < n; i += 1024) m = fmaxf(m, logits[i]);
    #pragma unroll
    for (int d = 32; d; d >>= 1) m = fmaxf(m, __shfl_xor(m, d));
    if (lane == 0) red[wv] = m;
    __syncthreads();
    if (tid == 0) {
        float mm = red[0];
        for (int i = 1; i < 16; ++i) mm = fmaxf(mm, red[i]);
        bc[0] = mm;
    }
    __syncthreads();
    const float M = bc[0];

    float s = 0.f;
    for (int i = tid; i < n; i += 1024) s += expf(logits[i] - M);
    #pragma unroll
    for (int d = 32; d; d >>= 1) s += __shfl_xor(s, d);
    if (lane == 0) red[wv] = s;
    __syncthreads();
    if (tid == 0) {
        float ss = 0.f;
        for (int i = 0; i < 16; ++i) ss += red[i];
        bc[1] = logf(ss);
    }
    __syncthreads();
    const float L = bc[1];
    for (int i = tid; i < n; i += 1024) out[i] = logits[i] - M - L;
}

// ---------------------------------------------------------------------------
// Workspace layout (bytes):
//   [0,        8192)   h double buffer (2 x 1024 f32)  -- zeroed each launch
//   [8192,     8448)   sync counter (+pad)             -- zeroed each launch
//   [8448,   209920)   logits (50257 f32, padded)
//   [209920, 16987136) xin   (4096 x 1024 f32)
//   [16987136, 67318784) gi  (4096 x 3072 f32)
// ---------------------------------------------------------------------------
extern "C" void kernel_launch(void* const* d_in, const int* in_sizes, int n_in,
                              void* d_out, int out_size, void* d_ws, size_t ws_size,
                              hipStream_t stream)
{
    const int*   tokens = (const int*)  d_in[0];
    const float* embed  = (const float*)d_in[1];
    const float* i2h_w  = (const float*)d_in[2];
    const float* i2h_b  = (const float*)d_in[3];
    const float* w_ih   = (const float*)d_in[4];
    const float* w_hh   = (const float*)d_in[5];
    const float* b_ih   = (const float*)d_in[6];
    const float* b_hh   = (const float*)d_in[7];
    const float* h2o_w  = (const float*)d_in[8];
    const float* h2o_b  = (const float*)d_in[9];
    float* out = (float*)d_out;

    char* Wb = (char*)d_ws;
    float*    hbuf   = (float*)(Wb);
    unsigned* cnt    = (unsigned*)(Wb + 8192);
    float*    logits = (float*)(Wb + 8448);
    float*    xin    = (float*)(Wb + 209920);
    float*    gi     = (float*)(Wb + 16987136);

    // zero h0 + counter (ws is poisoned 0xAA before every timed launch)
    hipMemsetAsync(Wb, 0, 8448, stream);

    // xin = embed[tokens] @ i2h_w^T + i2h_b        [4096,1024]
    gemm_nt<<<dim3(16, 64), 256, 0, stream>>>(nullptr, i2h_w, i2h_b, xin,
                                              TT, HH, II, tokens, embed);
    // gi = xin @ w_ih^T + b_ih                     [4096,3072]
    gemm_nt<<<dim3(48, 64), 256, 0, stream>>>(xin, w_ih, b_ih, gi,
                                              TT, 3 * HH, HH, nullptr, nullptr);
    // sequential GRU scan (final h lands in hbuf[0..1023], TT even)
    scan_gru<<<GWG, 512, 0, stream>>>(w_hh, b_hh, gi, hbuf, cnt);

    // logits + log_softmax
    logits_k<<<dim3((OO + 3) / 4), 256, 0, stream>>>(hbuf, h2o_w, h2o_b, logits, OO, HH);
    lsm_k<<<1, 1024, 0, stream>>>(logits, out, OO);
}